// Round 5
// baseline (171.961 us; speedup 1.0000x reference)
//
#include <hip/hip_runtime.h>
#include <stdint.h>

// Problem: out[m,e,k] = sum_n A[m,n] * W[e,n,k]
// == GEMM C[8192,2048] = A[8192,1024] x B[1024,2048], B[n, e*32+k] = W[e,n,k]
// Output flat layout m*2048 + e*32 + k matches [M,E,K] exactly.
//
// Round-5 structure: NO LDS, NO BARRIERS. Both A and B fragments load directly
// from global (L1/L2/L3-resident after first touch). Rationale: with B already
// direct (round 4 win), LDS gave A zero dedup (each staged byte read once) and
// cost the structural vmcnt(0)+s_barrier drain. Direct per-lane loads are full
// L2-line utilization: each A row's per-iter span (64 cols = 128B) is exactly
// one line, covered by the 8 lanes (4 quads x 2 halves) as dwordx4.
// Block 256x128, 4 waves 2x2, wave tile 128x64 = 8x4 of 16x16x32 MFMAs.

#define M_DIM 8192
#define N_IN  1024   // reduction dim
#define E_DIM 64
#define K_DIM 32
#define J_DIM 2048   // E*K output columns

typedef __attribute__((ext_vector_type(8))) __bf16 bf16x8;
typedef __attribute__((ext_vector_type(4))) float floatx4;

__device__ inline unsigned short f2bf(float f) {
    union { float f; unsigned u; } v; v.f = f;
    unsigned u = v.u;
    u += 0x7fff + ((u >> 16) & 1);   // round-to-nearest-even
    return (unsigned short)(u >> 16);
}

// A [8192,1024] f32 -> Ab bf16 (same row-major layout). 4 elements/thread.
__global__ __launch_bounds__(256) void convert_A(const float* __restrict__ A,
                                                 unsigned short* __restrict__ Ab) {
    size_t i = (size_t)blockIdx.x * 256 + threadIdx.x;
    const float4 v = ((const float4*)A)[i];
    ushort4 o;
    o.x = f2bf(v.x); o.y = f2bf(v.y); o.z = f2bf(v.z); o.w = f2bf(v.w);
    ((ushort4*)Ab)[i] = o;
}

// W [64][1024][32] f32 -> BG[kgroup=n>>3][j=e*32+k][t=n&7] bf16  (128 x 2048 x 8).
// B fragment for 16x16x32 MFMA: lane holds B^T[col j][k = kgroup*8 + t], t=0..7
// contiguous -> one 16B load per lane, lanes j-consecutive -> coalesced.
__global__ __launch_bounds__(256) void convert_W(const float* __restrict__ W,
                                                 unsigned short* __restrict__ BG) {
    const int t   = threadIdx.x;
    const int e   = blockIdx.y;        // 0..63
    const int n0  = blockIdx.x * 64;   // 16 slabs
    const int k   = t & 31;
    const int oct = t >> 5;            // 8 octets of n within the slab
    const float* Wp = W + ((size_t)e * N_IN + n0 + oct * 8) * K_DIM + k;
    unsigned short tmp[8];
#pragma unroll
    for (int u = 0; u < 8; ++u) tmp[u] = f2bf(Wp[(size_t)u * K_DIM]);  // coalesced per u
    unsigned short* out = BG + ((size_t)((n0 >> 3) + oct) * J_DIM + e * K_DIM + k) * 8;
    ushort4 lo, hi;
    lo.x = tmp[0]; lo.y = tmp[1]; lo.z = tmp[2]; lo.w = tmp[3];
    hi.x = tmp[4]; hi.y = tmp[5]; hi.z = tmp[6]; hi.w = tmp[7];
    ((ushort4*)out)[0] = lo;
    ((ushort4*)out)[1] = hi;           // 16B per thread, k-consecutive threads contiguous
}

__global__ __launch_bounds__(256, 2) void gemm_direct(const unsigned short* __restrict__ Ab,
                                                      const unsigned short* __restrict__ BG,
                                                      float* __restrict__ C) {
    const int tid  = threadIdx.x;
    const int wave = tid >> 6;
    const int lane = tid & 63;
    const int wm = wave >> 1, wn = wave & 1;
    const int m0 = blockIdx.x * 256;          // consecutive blocks share the B j-tile
    const int j0 = blockIdx.y * 128;
    const int l15  = lane & 15;
    const int quad = lane >> 4;

    floatx4 acc[8][4];
#pragma unroll
    for (int i = 0; i < 8; ++i)
#pragma unroll
        for (int j = 0; j < 4; ++j) acc[i][j] = (floatx4)(0.0f);

    // Per-lane bases.
    // A fragment (16x16x32): lane holds A[m = base+i*16+l15][k = kc + quad*8 .. +8)
    const unsigned short* Abase = Ab + (size_t)(m0 + wm * 128 + l15) * N_IN + quad * 8;
    // B fragment: lane holds B^T[col jcol+j*16][k = kc + quad*8 .. +8) via BG layout
    const int jcol = j0 + wn * 64 + l15;
    const unsigned short* Bbase = BG + (size_t)(quad * J_DIM + jcol) * 8;

    for (int kb = 0; kb < N_IN; kb += 64) {
        bf16x8 af[2][8], bfr[2][4];
        // Issue all 24 independent loads up front; compiler inserts fine-grained
        // vmcnt waits so h=0 MFMAs start while h=1 loads are in flight.
#pragma unroll
        for (int h = 0; h < 2; ++h) {
            const size_t koff = (size_t)(((kb + h * 32) >> 3)) * (J_DIM * 8);
#pragma unroll
            for (int j = 0; j < 4; ++j)
                bfr[h][j] = *(const bf16x8*)(Bbase + koff + (size_t)j * 16 * 8);
        }
#pragma unroll
        for (int h = 0; h < 2; ++h)
#pragma unroll
            for (int i = 0; i < 8; ++i)
                af[h][i] = *(const bf16x8*)(Abase + (size_t)i * 16 * N_IN + kb + h * 32);

#pragma unroll
        for (int h = 0; h < 2; ++h)
#pragma unroll
            for (int i = 0; i < 8; ++i)
#pragma unroll
                for (int j = 0; j < 4; ++j)
                    acc[i][j] = __builtin_amdgcn_mfma_f32_16x16x32_bf16(
                        af[h][i], bfr[h][j], acc[i][j], 0, 0, 0);
    }

    // Epilogue: C/D layout col = lane&15, row = (lane>>4)*4 + reg
    const int crow = quad * 4;
#pragma unroll
    for (int i = 0; i < 8; ++i) {
#pragma unroll
        for (int j = 0; j < 4; ++j) {
            float* Cp = C + (size_t)(m0 + wm * 128 + i * 16 + crow) * J_DIM
                          + (jcol + j * 16);
#pragma unroll
            for (int r = 0; r < 4; ++r)
                Cp[(size_t)r * J_DIM] = acc[i][j][r];
        }
    }
}

extern "C" void kernel_launch(void* const* d_in, const int* in_sizes, int n_in,
                              void* d_out, int out_size, void* d_ws, size_t ws_size,
                              hipStream_t stream) {
    const float* A = (const float*)d_in[0];   // [8192,1024]
    const float* W = (const float*)d_in[1];   // [64,1024,32]
    float* out = (float*)d_out;               // [8192,64,32] == [8192,2048]

    unsigned short* Ab = (unsigned short*)d_ws;                 // 16 MB
    unsigned short* BG = Ab + (size_t)M_DIM * N_IN;             // +4 MB

    convert_A<<<M_DIM * N_IN / (256 * 4), 256, 0, stream>>>(A, Ab);
    convert_W<<<dim3(N_IN / 64, E_DIM), 256, 0, stream>>>(W, BG);
    gemm_direct<<<dim3(M_DIM / 256, J_DIM / 128), 256, 0, stream>>>(Ab, BG, out);
}

// Round 6
// 130.776 us; speedup vs baseline: 1.3149x; 1.3149x over previous
//
#include <hip/hip_runtime.h>
#include <stdint.h>

// Problem: out[m,e,k] = sum_n A[m,n] * W[e,n,k]
// == GEMM C[8192,2048] = A[8192,1024] x B[1024,2048], B[n, e*32+k] = W[e,n,k]
// Output flat layout m*2048 + e*32 + k matches [M,E,K] exactly.
//
// Round-6 structure (round-4 + async dbuf):
//  - A staged via global_load_lds DMA (deep queue = latency hiding; round-5
//    proved direct per-lane A loads are latency-bound at 84 us), XOR-swizzled
//    LDS (conflict-free, verified SQ_LDS_BANK_CONFLICT==0).
//  - B fragments DIRECT from global (4 MB, L2-resident, reused 32x) in
//    k-group-major layout BG[kgroup][j][8] (round-4 win).
//  - NEW: double-buffered A (64 KB LDS), ONE barrier per iter; the k+1 DMA is
//    issued after the barrier and flies under iter k's 64 MFMAs, so the
//    vmcnt(0)+s_barrier drain no longer serializes staging with compute.
// Block 256x128, 4 waves 2x2, wave tile 128x64 = 8x4 of 16x16x32 MFMAs.

#define M_DIM 8192
#define N_IN  1024   // reduction dim
#define E_DIM 64
#define K_DIM 32
#define J_DIM 2048   // E*K output columns

typedef __attribute__((ext_vector_type(8))) __bf16 bf16x8;
typedef __attribute__((ext_vector_type(4))) float floatx4;

__device__ inline unsigned short f2bf(float f) {
    union { float f; unsigned u; } v; v.f = f;
    unsigned u = v.u;
    u += 0x7fff + ((u >> 16) & 1);   // round-to-nearest-even
    return (unsigned short)(u >> 16);
}

// A [8192,1024] f32 -> Ab bf16 (same row-major layout). 4 elements/thread.
__global__ __launch_bounds__(256) void convert_A(const float* __restrict__ A,
                                                 unsigned short* __restrict__ Ab) {
    size_t i = (size_t)blockIdx.x * 256 + threadIdx.x;
    const float4 v = ((const float4*)A)[i];
    ushort4 o;
    o.x = f2bf(v.x); o.y = f2bf(v.y); o.z = f2bf(v.z); o.w = f2bf(v.w);
    ((ushort4*)Ab)[i] = o;
}

// W [64][1024][32] f32 -> BG[kgroup=n>>3][j=e*32+k][t=n&7] bf16  (128 x 2048 x 8).
// B fragment for 16x16x32 MFMA: lane holds B^T[col j][k = kgroup*8 + t], t=0..7
// contiguous -> one 16B load per lane, lanes j-consecutive -> coalesced.
__global__ __launch_bounds__(256) void convert_W(const float* __restrict__ W,
                                                 unsigned short* __restrict__ BG) {
    const int t   = threadIdx.x;
    const int e   = blockIdx.y;        // 0..63
    const int n0  = blockIdx.x * 64;   // 16 slabs
    const int k   = t & 31;
    const int oct = t >> 5;            // 8 octets of n within the slab
    const float* Wp = W + ((size_t)e * N_IN + n0 + oct * 8) * K_DIM + k;
    unsigned short tmp[8];
#pragma unroll
    for (int u = 0; u < 8; ++u) tmp[u] = f2bf(Wp[(size_t)u * K_DIM]);  // coalesced per u
    unsigned short* out = BG + ((size_t)((n0 >> 3) + oct) * J_DIM + e * K_DIM + k) * 8;
    ushort4 lo, hi;
    lo.x = tmp[0]; lo.y = tmp[1]; lo.z = tmp[2]; lo.w = tmp[3];
    hi.x = tmp[4]; hi.y = tmp[5]; hi.z = tmp[6]; hi.w = tmp[7];
    ((ushort4*)out)[0] = lo;
    ((ushort4*)out)[1] = hi;           // 16B per thread, k-consecutive threads contiguous
}

__global__ __launch_bounds__(256, 2) void gemm_bt(const unsigned short* __restrict__ Ab,
                                                  const unsigned short* __restrict__ BG,
                                                  float* __restrict__ C) {
    __shared__ unsigned short As[2][256 * 64];   // 2 x 32 KB, XOR-swizzled rows

    const int tid  = threadIdx.x;
    const int wave = tid >> 6;
    const int lane = tid & 63;
    const int wm = wave >> 1, wn = wave & 1;
    const int m0 = blockIdx.x * 256;          // consecutive blocks share the B j-tile
    const int j0 = blockIdx.y * 128;

    floatx4 acc[8][4];
#pragma unroll
    for (int i = 0; i < 8; ++i)
#pragma unroll
        for (int j = 0; j < 4; ++j) acc[i][j] = (floatx4)(0.0f);

    // Staging geometry: 32 chunks of 1KB (8 rows x 64 cols). Lane l covers LDS
    // slot (row_in_chunk = l>>3, group = l&7); fetches swizzled global group
    // (l&7)^(l>>3) so fragment reads (group g of row r at slot g^(r&7)) work.
    const int lrow8 = lane >> 3;
    const int gcol  = ((lane & 7) ^ lrow8) * 8;
    const int l15  = lane & 15;
    const int quad = lane >> 4;
    const int l7   = lane & 7;
    const int jcol = j0 + wn * 64 + l15;      // per-lane B column

    const unsigned short* arow = Ab + (size_t)m0 * N_IN + gcol;  // + row*N_IN + kb

#define STAGE_A(KB, BUF)                                                        \
    do {                                                                        \
        _Pragma("unroll")                                                       \
        for (int l = 0; l < 8; ++l) {                                           \
            const int chunk = l * 4 + wave;                                     \
            const int row   = chunk * 8 + lrow8;                                \
            const unsigned short* ga = arow + (size_t)row * N_IN + (KB);        \
            __builtin_amdgcn_global_load_lds(                                   \
                (const __attribute__((address_space(1))) unsigned int*)ga,      \
                (__attribute__((address_space(3))) unsigned int*)               \
                    (As[BUF] + chunk * 512),                                    \
                16, 0, 0);                                                      \
        }                                                                       \
    } while (0)

    STAGE_A(0, 0);

    for (int kb = 0; kb < N_IN; kb += 64) {
        const int buf = (kb >> 6) & 1;
        // B fragments for both k-halves, direct from global (L2-hot), issued
        // before the barrier so their latency hides under the drain.
        bf16x8 bfr[2][4];
#pragma unroll
        for (int h = 0; h < 2; ++h) {
            const size_t koff = (size_t)((kb + h * 32) >> 3) * (J_DIM * 8);
#pragma unroll
            for (int j = 0; j < 4; ++j)
                bfr[h][j] = *(const bf16x8*)(BG + koff + ((size_t)quad * J_DIM + jcol + j * 16) * 8);
        }
        // Barrier: (a) each wave's own DMA for `buf` has drained (vmcnt(0)
        // before s_barrier), so As[buf] is fully staged; (b) all waves have
        // finished reading As[buf^1] from the previous iter, so the prefetch
        // issued below cannot race a reader.
        __syncthreads();
        if (kb + 64 < N_IN) STAGE_A(kb + 64, buf ^ 1);

#pragma unroll
        for (int h = 0; h < 2; ++h) {
            const int sg = (((h * 4) + quad) ^ l7) * 8;   // (k-group) ^ (row&7)
#pragma unroll
            for (int i = 0; i < 8; ++i) {
                const bf16x8 af = *(const bf16x8*)(As[buf] + (wm * 128 + i * 16 + l15) * 64 + sg);
#pragma unroll
                for (int j = 0; j < 4; ++j)
                    acc[i][j] = __builtin_amdgcn_mfma_f32_16x16x32_bf16(
                        af, bfr[h][j], acc[i][j], 0, 0, 0);
            }
        }
    }
#undef STAGE_A

    // Epilogue: C/D layout col = lane&15, row = (lane>>4)*4 + reg
    const int crow = quad * 4;
#pragma unroll
    for (int i = 0; i < 8; ++i) {
#pragma unroll
        for (int j = 0; j < 4; ++j) {
            float* Cp = C + (size_t)(m0 + wm * 128 + i * 16 + crow) * J_DIM
                          + (jcol + j * 16);
#pragma unroll
            for (int r = 0; r < 4; ++r)
                Cp[(size_t)r * J_DIM] = acc[i][j][r];
        }
    }
}

extern "C" void kernel_launch(void* const* d_in, const int* in_sizes, int n_in,
                              void* d_out, int out_size, void* d_ws, size_t ws_size,
                              hipStream_t stream) {
    const float* A = (const float*)d_in[0];   // [8192,1024]
    const float* W = (const float*)d_in[1];   // [64,1024,32]
    float* out = (float*)d_out;               // [8192,64,32] == [8192,2048]

    unsigned short* Ab = (unsigned short*)d_ws;                 // 16 MB
    unsigned short* BG = Ab + (size_t)M_DIM * N_IN;             // +4 MB

    convert_A<<<M_DIM * N_IN / (256 * 4), 256, 0, stream>>>(A, Ab);
    convert_W<<<dim3(N_IN / 64, E_DIM), 256, 0, stream>>>(W, BG);
    gemm_bt<<<dim3(M_DIM / 256, J_DIM / 128), 256, 0, stream>>>(Ab, BG, out);
}